// Round 1
// baseline (190.489 us; speedup 1.0000x reference)
//
#include <hip/hip_runtime.h>
#include <hip/hip_bf16.h>

// Problem: B=8, Cin=Cout=32, H=W=256, K=5 (all bins length 52, pad 2 symmetric)
// out[b,o,y,x] = sum_{kh,kw} filt[b,o,kh,kw] * feat[b,o,y-2+kh,x-2+kw]   (cross-corr, zero pad)
// feat = conv1x1(x, W) + bias ; filt = adaptive_avg_pool2d(feat, 5)

#define CIN 32
#define COUT 32
#define HW 256
#define PLANE (HW * HW)          // 65536
#define BATCH 8
#define KF 5

// ---------------- K1: 1x1 conv (channel mix). Each thread: 2 rows x 1 col. ----------------
__global__ __launch_bounds__(256) void conv1x1_kernel(const float* __restrict__ x,
                                                      const float* __restrict__ Wm,
                                                      const float* __restrict__ bias,
                                                      float* __restrict__ feat) {
    int b  = blockIdx.x >> 7;        // 0..7
    int hp = blockIdx.x & 127;       // 0..127  (pair of rows)
    int h0 = hp * 2;
    int w  = threadIdx.x;            // 0..255

    const float* xb = x + (size_t)b * CIN * PLANE + h0 * HW + w;
    float xv0[CIN], xv1[CIN];
#pragma unroll
    for (int i = 0; i < CIN; ++i) {
        xv0[i] = xb[i * PLANE];
        xv1[i] = xb[i * PLANE + HW];
    }
    float* fb = feat + (size_t)b * COUT * PLANE + h0 * HW + w;
#pragma unroll 4
    for (int o = 0; o < COUT; ++o) {
        float a0 = bias[o];          // uniform -> SGPR
        float a1 = a0;
#pragma unroll
        for (int i = 0; i < CIN; ++i) {
            float wv = Wm[o * CIN + i];   // uniform index -> s_load, stays scalar
            a0 += wv * xv0[i];
            a1 += wv * xv1[i];
        }
        fb[o * PLANE] = a0;
        fb[o * PLANE + HW] = a1;
    }
}

// ---------------- K2: adaptive avg pool feat -> filt[b*32+o][25] ----------------
// One block per (bo, k-bin). Threads = columns; column partial sums over the k row-bin,
// then 5 threads fold columns into the 5 l-bins.
__global__ __launch_bounds__(256) void pool_kernel(const float* __restrict__ feat,
                                                   float* __restrict__ filt) {
    int bo = blockIdx.x / KF;
    int k  = blockIdx.x % KF;
    int sk = (k * HW) / KF;
    int ek = ((k + 1) * HW + KF - 1) / KF;   // ceil
    int t  = threadIdx.x;

    const float* f = feat + (size_t)bo * PLANE + t;
    float cs = 0.f;
    for (int h = sk; h < ek; ++h) cs += f[h * HW];

    __shared__ float col[256];
    col[t] = cs;
    __syncthreads();

    if (t < KF) {
        int sl = (t * HW) / KF;
        int el = ((t + 1) * HW + KF - 1) / KF;
        float s = 0.f;
        for (int w2 = sl; w2 < el; ++w2) s += col[w2];
        filt[bo * (KF * KF) + k * KF + t] = s / (float)((ek - sk) * (el - sl));
    }
}

// ---------------- K3: depthwise 5x5 conv, 32x32 tile, 36x36 halo in LDS (column-major) ----
__global__ __launch_bounds__(256) void dwconv_kernel(const float* __restrict__ feat,
                                                     const float* __restrict__ filt,
                                                     float* __restrict__ out) {
    int bo   = blockIdx.y;                 // 0..255  (b*32+o)
    int tile = blockIdx.x;                 // 0..63
    int ty   = tile >> 3, tx_ = tile & 7;
    int oy0  = ty * 32, ox0 = tx_ * 32;

    __shared__ __align__(16) float s[36 * 36];  // [col][row], col stride 36 floats (144B, 16B-aligned)
    __shared__ float sfilt[25];

    const float* fb = feat + (size_t)bo * PLANE;
    int t = threadIdx.x;
    if (t < 25) sfilt[t] = filt[bo * 25 + t];

    for (int idx = t; idx < 36 * 36; idx += 256) {
        int r = idx / 36;
        int c = idx - r * 36;
        int gy = oy0 - 2 + r;
        int gx = ox0 - 2 + c;
        float v = 0.f;
        if ((unsigned)gy < (unsigned)HW && (unsigned)gx < (unsigned)HW) v = fb[gy * HW + gx];
        s[c * 36 + r] = v;                 // transposed store
    }
    __syncthreads();

    float f[25];
#pragma unroll
    for (int j = 0; j < 25; ++j) f[j] = sfilt[j];   // LDS broadcast, once

    int tx = t & 31;        // output col within tile
    int tq = t >> 5;        // 0..7 -> output rows 4tq..4tq+3
    float acc0 = 0.f, acc1 = 0.f, acc2 = 0.f, acc3 = 0.f;

#pragma unroll
    for (int kw = 0; kw < 5; ++kw) {
        const float* colp = &s[(tx + kw) * 36 + 4 * tq];
        float4 lo = *(const float4*)(colp);       // rows 4tq..4tq+3
        float4 hi = *(const float4*)(colp + 4);   // rows 4tq+4..4tq+7
        float r0 = lo.x, r1 = lo.y, r2 = lo.z, r3 = lo.w;
        float r4 = hi.x, r5 = hi.y, r6 = hi.z, r7 = hi.w;
#pragma unroll
        for (int kh = 0; kh < 5; ++kh) {
            float wv = f[kh * 5 + kw];
            float v0 = (kh == 0) ? r0 : (kh == 1) ? r1 : (kh == 2) ? r2 : (kh == 3) ? r3 : r4;
            float v1 = (kh == 0) ? r1 : (kh == 1) ? r2 : (kh == 2) ? r3 : (kh == 3) ? r4 : r5;
            float v2 = (kh == 0) ? r2 : (kh == 1) ? r3 : (kh == 2) ? r4 : (kh == 3) ? r5 : r6;
            float v3 = (kh == 0) ? r3 : (kh == 1) ? r4 : (kh == 2) ? r5 : (kh == 3) ? r6 : r7;
            acc0 += wv * v0;
            acc1 += wv * v1;
            acc2 += wv * v2;
            acc3 += wv * v3;
        }
    }

    float* ob = out + (size_t)bo * PLANE;
    int gx = ox0 + tx;
    int gy = oy0 + 4 * tq;
    ob[(gy + 0) * HW + gx] = acc0;
    ob[(gy + 1) * HW + gx] = acc1;
    ob[(gy + 2) * HW + gx] = acc2;
    ob[(gy + 3) * HW + gx] = acc3;
}

extern "C" void kernel_launch(void* const* d_in, const int* in_sizes, int n_in,
                              void* d_out, int out_size, void* d_ws, size_t ws_size,
                              hipStream_t stream) {
    const float* x      = (const float*)d_in[0];
    const float* conv_w = (const float*)d_in[1];
    const float* conv_b = (const float*)d_in[2];
    float* out = (float*)d_out;

    float* feat = (float*)d_ws;                           // 8*32*65536 floats = 64 MiB
    float* filt = feat + (size_t)BATCH * COUT * PLANE;    // 6400 floats

    // K1: 1x1 conv
    conv1x1_kernel<<<dim3(BATCH * 128), dim3(256), 0, stream>>>(x, conv_w, conv_b, feat);
    // K2: adaptive pool -> filters
    pool_kernel<<<dim3(BATCH * COUT * KF), dim3(256), 0, stream>>>(feat, filt);
    // K3: depthwise 5x5
    dwconv_kernel<<<dim3(64, BATCH * COUT), dim3(256), 0, stream>>>(feat, filt, out);
}

// Round 2
// 188.682 us; speedup vs baseline: 1.0096x; 1.0096x over previous
//
#include <hip/hip_runtime.h>

// B=8, Cin=Cout=32, H=W=256, K=5. All adaptive bins are length 52, start (k*256)/5.
// out[b,o,y,x] = sum_{kh,kw} filt[b,o,kh,kw] * feat[b,o,y-2+kh,x-2+kw]  (zero pad 2)

#define CIN 32
#define COUT 32
#define HW 256
#define PLANE (HW * HW)
#define BATCH 8
#define KF 5
#define BIN 52

// ---------------- K1: 1x1 conv. Thread = 4 consecutive pixels (float4). ----------------
__global__ __launch_bounds__(256) void conv1x1_kernel(const float* __restrict__ x,
                                                      const float* __restrict__ Wm,
                                                      const float* __restrict__ bias,
                                                      float* __restrict__ feat) {
    int b  = blockIdx.x >> 6;        // 0..7
    int rg = blockIdx.x & 63;        // 0..63 (4-row group)
    int p0 = rg * 1024 + threadIdx.x * 4;

    const float* xb = x + (size_t)b * CIN * PLANE + p0;
    float4 xv[CIN];
#pragma unroll
    for (int i = 0; i < CIN; ++i) xv[i] = *(const float4*)(xb + (size_t)i * PLANE);

    float* fb = feat + (size_t)b * COUT * PLANE + p0;
#pragma unroll 4
    for (int o = 0; o < COUT; ++o) {
        float bv = bias[o];
        float4 a; a.x = bv; a.y = bv; a.z = bv; a.w = bv;
#pragma unroll
        for (int i = 0; i < CIN; ++i) {
            float wv = Wm[o * CIN + i];    // uniform -> scalar load
            a.x += wv * xv[i].x; a.y += wv * xv[i].y;
            a.z += wv * xv[i].z; a.w += wv * xv[i].w;
        }
        *(float4*)(fb + (size_t)o * PLANE) = a;
    }
}

// ---------------- K2: adaptive pool -> filt[bo][25], float4 loads + 2-stage LDS reduce ----
__global__ __launch_bounds__(256) void pool_kernel(const float* __restrict__ feat,
                                                   float* __restrict__ filt) {
    int bo = blockIdx.x / KF;
    int k  = blockIdx.x % KF;
    int sk = (k * HW) / KF;
    int t  = threadIdx.x;
    int c4 = t & 63;        // float4 column group
    int rq = t >> 6;        // 0..3 row phase

    const float* f = feat + (size_t)bo * PLANE + (sk + rq) * HW + c4 * 4;
    float4 a = {0.f, 0.f, 0.f, 0.f};
#pragma unroll
    for (int j = 0; j < 13; ++j) {       // rows rq, rq+4, ..., rq+48 -> all 52 rows
        float4 v = *(const float4*)(f + j * 4 * HW);
        a.x += v.x; a.y += v.y; a.z += v.z; a.w += v.w;
    }

    __shared__ float4 red[256];
    __shared__ float cols[256];
    red[t] = a;
    __syncthreads();
    if (t < 64) {
        float4 r0 = red[t], r1 = red[t + 64], r2 = red[t + 128], r3 = red[t + 192];
        cols[4 * t + 0] = r0.x + r1.x + r2.x + r3.x;
        cols[4 * t + 1] = r0.y + r1.y + r2.y + r3.y;
        cols[4 * t + 2] = r0.z + r1.z + r2.z + r3.z;
        cols[4 * t + 3] = r0.w + r1.w + r2.w + r3.w;
    }
    __syncthreads();
    if (t < KF) {
        int sl = (t * HW) / KF;
        float s = 0.f;
        for (int w = 0; w < BIN; ++w) s += cols[sl + w];
        filt[bo * 25 + k * KF + t] = s * (1.0f / (BIN * BIN));
    }
}

// ---------------- K3: depthwise 5x5, 32-row x 256-col strips, register sliding window ----
#define LROW 264   // LDS row stride (floats); interior col x at [lr*LROW + 4 + x]
__global__ __launch_bounds__(256) void dwconv_kernel(const float* __restrict__ feat,
                                                     const float* __restrict__ filt,
                                                     float* __restrict__ out) {
    int bo    = blockIdx.y;            // 0..255
    int strip = blockIdx.x;            // 0..7
    int gy0   = strip * 32;
    int t     = threadIdx.x;

    __shared__ __align__(16) float s[36 * LROW];
    __shared__ float sfilt[25];
    if (t < 25) sfilt[t] = filt[bo * 25 + t];
    // zero the 2-col pads (LDS idx 2,3 and 260,261) on each of 36 rows
    if (t < 144) {
        int lr = t >> 2, e = t & 3;
        int ci = (e < 2) ? (2 + e) : (258 + e);
        s[lr * LROW + ci] = 0.f;
    }

    const float* fb = feat + (size_t)bo * PLANE;
#pragma unroll
    for (int j = 0; j < 9; ++j) {          // 36 rows x 64 float4 = 2304 / 256 threads
        int idx = t + 256 * j;
        int lr  = idx >> 6;
        int cx  = (idx & 63) * 4;
        int gy  = gy0 - 2 + lr;
        float4 v = {0.f, 0.f, 0.f, 0.f};
        if ((unsigned)gy < (unsigned)HW) v = *(const float4*)(fb + gy * HW + cx);
        *(float4*)(&s[lr * LROW + 4 + cx]) = v;
    }
    __syncthreads();

    float fw[25];
#pragma unroll
    for (int j = 0; j < 25; ++j) fw[j] = sfilt[j];   // LDS broadcast once

    int c = t;   // output column
    // sliding 5x5 window: wK[j] = feat row (gy0 + r - 2 + K) at col c - 2 + j
    float w0[5], w1[5], w2[5], w3[5], w4[5];
#pragma unroll
    for (int j = 0; j < 5; ++j) {
        w0[j] = s[0 * LROW + 2 + c + j];
        w1[j] = s[1 * LROW + 2 + c + j];
        w2[j] = s[2 * LROW + 2 + c + j];
        w3[j] = s[3 * LROW + 2 + c + j];
    }
    float* ob = out + (size_t)bo * PLANE + (size_t)gy0 * HW + c;
#pragma unroll
    for (int r = 0; r < 32; ++r) {
#pragma unroll
        for (int j = 0; j < 5; ++j) w4[j] = s[(r + 4) * LROW + 2 + c + j];
        float acc = 0.f;
#pragma unroll
        for (int j = 0; j < 5; ++j) {
            acc += fw[0 * 5 + j] * w0[j];
            acc += fw[1 * 5 + j] * w1[j];
            acc += fw[2 * 5 + j] * w2[j];
            acc += fw[3 * 5 + j] * w3[j];
            acc += fw[4 * 5 + j] * w4[j];
        }
        ob[r * HW] = acc;
#pragma unroll
        for (int j = 0; j < 5; ++j) {    // renamed away under full unroll
            w0[j] = w1[j]; w1[j] = w2[j]; w2[j] = w3[j]; w3[j] = w4[j];
        }
    }
}

extern "C" void kernel_launch(void* const* d_in, const int* in_sizes, int n_in,
                              void* d_out, int out_size, void* d_ws, size_t ws_size,
                              hipStream_t stream) {
    const float* x      = (const float*)d_in[0];
    const float* conv_w = (const float*)d_in[1];
    const float* conv_b = (const float*)d_in[2];
    float* out = (float*)d_out;

    float* feat = (float*)d_ws;                           // 64 MiB
    float* filt = feat + (size_t)BATCH * COUT * PLANE;    // 6400 floats

    conv1x1_kernel<<<dim3(BATCH * 64), dim3(256), 0, stream>>>(x, conv_w, conv_b, feat);
    pool_kernel<<<dim3(BATCH * COUT * KF), dim3(256), 0, stream>>>(feat, filt);
    dwconv_kernel<<<dim3(8, BATCH * COUT), dim3(256), 0, stream>>>(feat, filt, out);
}

// Round 3
// 156.928 us; speedup vs baseline: 1.2139x; 1.2023x over previous
//
#include <hip/hip_runtime.h>

// B=8, Cin=Cout=32, H=W=256, K=5. Adaptive bins: start (k*256)/5 = {0,51,102,153,204},
// all length 52 (bins overlap by 1 row/col). filt = pooled feat / 52^2.
// out[b,o,y,x] = sum_{kh,kw} filt[b,o,kh,kw] * feat[b,o,y-2+kh,x-2+kw]  (zero pad 2)

#define CIN 32
#define COUT 32
#define HW 256
#define PLANE (HW * HW)
#define BATCH 8
#define KF 5
#define BIN 52

// ---------------- K1: 1x1 conv + fused adaptive-pool partial sums ----------------
// Block = one (b, row); 256 threads = 256 cols. x staged via float4 into LDS
// (keeps VGPRs ~70, gives bulk MLP); acc[32] per pixel; pooling reduced in LDS
// then atomicAdd into filt_raw (zeroed by memset before launch).
__global__ __launch_bounds__(256) void conv1x1_pool_kernel(const float* __restrict__ x,
                                                           const float* __restrict__ Wm,
                                                           const float* __restrict__ bias,
                                                           float* __restrict__ feat,
                                                           float* __restrict__ filt_raw) {
    int b   = blockIdx.x >> 8;      // 0..7
    int row = blockIdx.x & 255;     // 0..255
    int t   = threadIdx.x;

    __shared__ __align__(16) float lds[CIN * HW];   // 32 KB: x stage, reused as pool scratch

    // stage x[b][*][row][*]: 8 float4 loads per thread, fully coalesced 1KB segments
    const float* xb = x + (size_t)b * CIN * PLANE + row * HW;
#pragma unroll
    for (int j = 0; j < 8; ++j) {
        int idx = t + 256 * j;            // 0..2047
        int ch  = idx >> 6;               // 0..31
        int c4  = (idx & 63) << 2;        // 0..252
        *(float4*)&lds[ch * HW + c4] = *(const float4*)(xb + (size_t)ch * PLANE + c4);
    }
    __syncthreads();

    float acc[COUT];
#pragma unroll
    for (int o = 0; o < COUT; ++o) acc[o] = bias[o];
#pragma unroll
    for (int i = 0; i < CIN; ++i) {
        float xi = lds[i * HW + t];       // conflict-free (consecutive lanes)
#pragma unroll
        for (int o = 0; o < COUT; ++o) acc[o] += Wm[o * CIN + i] * xi;   // W uniform -> s_load
    }

    // write feat: 32 coalesced dword stores
    float* fb = feat + (size_t)b * COUT * PLANE + row * HW + t;
#pragma unroll
    for (int o = 0; o < COUT; ++o) fb[(size_t)o * PLANE] = acc[o];

    // ---- fused pooling: this row's contribution to filt ----
    __syncthreads();                       // done reading x stage
#pragma unroll
    for (int o = 0; o < COUT; ++o) lds[o * HW + t] = acc[o];
    __syncthreads();

    if (t < COUT * KF) {                   // 160 jobs: (o, xbin l)
        int o  = t / KF;
        int l  = t - o * KF;
        int sl = (l * HW) / KF;
        float s = 0.f;
        for (int w = 0; w < BIN; ++w) s += lds[o * HW + sl + w];
        float* dst = filt_raw + (size_t)(b * COUT + o) * 25 + l;
#pragma unroll
        for (int k = 0; k < KF; ++k) {     // row may belong to 1 or 2 y-bins
            int sk = (k * HW) / KF;
            if (row >= sk && row < sk + BIN) atomicAdd(dst + k * KF, s);
        }
    }
}

// ---------------- K3: depthwise 5x5, 32-row x 256-col strips, register sliding window ----
#define LROW 264   // LDS row stride (floats); interior col x at [lr*LROW + 4 + x]
__global__ __launch_bounds__(256) void dwconv_kernel(const float* __restrict__ feat,
                                                     const float* __restrict__ filt_raw,
                                                     float* __restrict__ out) {
    int bo    = blockIdx.y;            // 0..255
    int strip = blockIdx.x;            // 0..7
    int gy0   = strip * 32;
    int t     = threadIdx.x;

    __shared__ __align__(16) float s[36 * LROW];
    __shared__ float sfilt[25];
    if (t < 25) sfilt[t] = filt_raw[bo * 25 + t] * (1.0f / (52.0f * 52.0f));
    // zero the 2-col pads (LDS idx 2,3 and 260,261) on each of 36 rows
    if (t < 144) {
        int lr = t >> 2, e = t & 3;
        int ci = (e < 2) ? (2 + e) : (258 + e);
        s[lr * LROW + ci] = 0.f;
    }

    const float* fb = feat + (size_t)bo * PLANE;
#pragma unroll
    for (int j = 0; j < 9; ++j) {          // 36 rows x 64 float4 = 2304 / 256 threads
        int idx = t + 256 * j;
        int lr  = idx >> 6;
        int cx  = (idx & 63) * 4;
        int gy  = gy0 - 2 + lr;
        float4 v = {0.f, 0.f, 0.f, 0.f};
        if ((unsigned)gy < (unsigned)HW) v = *(const float4*)(fb + gy * HW + cx);
        *(float4*)(&s[lr * LROW + 4 + cx]) = v;
    }
    __syncthreads();

    float fw[25];
#pragma unroll
    for (int j = 0; j < 25; ++j) fw[j] = sfilt[j];   // LDS broadcast once

    int c = t;   // output column
    float w0[5], w1[5], w2[5], w3[5], w4[5];
#pragma unroll
    for (int j = 0; j < 5; ++j) {
        w0[j] = s[0 * LROW + 2 + c + j];
        w1[j] = s[1 * LROW + 2 + c + j];
        w2[j] = s[2 * LROW + 2 + c + j];
        w3[j] = s[3 * LROW + 2 + c + j];
    }
    float* ob = out + (size_t)bo * PLANE + (size_t)gy0 * HW + c;
#pragma unroll
    for (int r = 0; r < 32; ++r) {
#pragma unroll
        for (int j = 0; j < 5; ++j) w4[j] = s[(r + 4) * LROW + 2 + c + j];
        float acc = 0.f;
#pragma unroll
        for (int j = 0; j < 5; ++j) {
            acc += fw[0 * 5 + j] * w0[j];
            acc += fw[1 * 5 + j] * w1[j];
            acc += fw[2 * 5 + j] * w2[j];
            acc += fw[3 * 5 + j] * w3[j];
            acc += fw[4 * 5 + j] * w4[j];
        }
        ob[r * HW] = acc;
#pragma unroll
        for (int j = 0; j < 5; ++j) {      // renamed away under full unroll
            w0[j] = w1[j]; w1[j] = w2[j]; w2[j] = w3[j]; w3[j] = w4[j];
        }
    }
}

extern "C" void kernel_launch(void* const* d_in, const int* in_sizes, int n_in,
                              void* d_out, int out_size, void* d_ws, size_t ws_size,
                              hipStream_t stream) {
    const float* x      = (const float*)d_in[0];
    const float* conv_w = (const float*)d_in[1];
    const float* conv_b = (const float*)d_in[2];
    float* out = (float*)d_out;

    float* feat = (float*)d_ws;                           // 64 MiB
    float* filt = feat + (size_t)BATCH * COUT * PLANE;    // 6400 floats (raw sums)

    hipMemsetAsync(filt, 0, BATCH * COUT * 25 * sizeof(float), stream);
    conv1x1_pool_kernel<<<dim3(BATCH * 256), dim3(256), 0, stream>>>(x, conv_w, conv_b, feat, filt);
    dwconv_kernel<<<dim3(8, BATCH * COUT), dim3(256), 0, stream>>>(feat, filt, out);
}